// Round 4
// baseline (154.714 us; speedup 1.0000x reference)
//
#include <hip/hip_runtime.h>
#include <hip/hip_bf16.h>
#include <stdint.h>

#define S_LEN 2048
#define D_DIM 1024
#define P_DIM 256
#define NQ_   8192
#define M_TOT 16384  // B*S

#define BM 64
#define BN 256
#define BK 64
#define CAP 32       // max span-endpoints per H row (lambda=2, P(>32)~1e-26)
#define HS  260      // padded f32 row stride for H tile in LDS

typedef __attribute__((ext_vector_type(4))) float  f32x4;
typedef __attribute__((ext_vector_type(8))) __bf16 bf16x8;

__device__ __forceinline__ void async16(const void* g, void* l) {
    __builtin_amdgcn_global_load_lds(
        (const __attribute__((address_space(1))) uint32_t*)g,
        (__attribute__((address_space(3))) uint32_t*)l, 16, 0, 0);
}

// ---------------- Kernel 0: W [1024][256] f32 -> WT [256][1024] bf16 ----------
// Also zeroes the 16384-entry row-bucket counters.
__global__ __launch_bounds__(1024) void wt_kernel(const float* __restrict__ W,
                                                  __bf16* __restrict__ WT,
                                                  int* __restrict__ cnt) {
    __shared__ __bf16 tile[32][33];
    const int k0 = blockIdx.x * 32;
    const int n0 = blockIdx.y * 32;
    const int tx = threadIdx.x, ty = threadIdx.y;
    const int g = (blockIdx.y * gridDim.x + blockIdx.x) * 1024 + ty * 32 + tx;
    if (g < M_TOT) cnt[g] = 0;
    tile[ty][tx] = (__bf16)W[(k0 + ty) * P_DIM + (n0 + tx)];
    __syncthreads();
    WT[(n0 + ty) * D_DIM + (k0 + tx)] = tile[tx][ty];
}

// ---------------- Kernel 1: inverted span index + invalid-span zeroing --------
__global__ __launch_bounds__(256) void index_zero(const int* __restrict__ s1,
                                                  const int* __restrict__ e1,
                                                  const int* __restrict__ s2,
                                                  const int* __restrict__ e2,
                                                  const int* __restrict__ qb,
                                                  int* __restrict__ cnt,
                                                  int* __restrict__ bucket,
                                                  float* __restrict__ out) {
    const int q    = blockIdx.x * 256 + threadIdx.x;
    const int lane = threadIdx.x & 63;
    const int bqw  = blockIdx.x * 256 + (threadIdx.x & ~63);  // wave's first q
    const int b    = qb[q];
    const float4 z = make_float4(0.f, 0.f, 0.f, 0.f);
    #pragma unroll
    for (int set = 0; set < 2; ++set) {
        const int s = set ? s2[q] : s1[q];
        const int e = set ? e2[q] : e1[q];
        if (e >= s) {
            int r = b * S_LEN + s;
            int k = atomicAdd(&cnt[r], 1); if (k < CAP) bucket[r * CAP + k] = (q << 2) | (set << 1);
            r = b * S_LEN + e;
            k = atomicAdd(&cnt[r], 1);     if (k < CAP) bucket[r * CAP + k] = (q << 2) | (set << 1) | 1;
        }
        unsigned long long mask = __ballot(e < s);
        while (mask) {
            const int j = __ffsll(mask) - 1;
            mask &= mask - 1;
            const int qz = bqw + j;
            float4* dst = (float4*)(out + (size_t)set * (NQ_ * 512) + (size_t)qz * 512);
            dst[lane]      = z;
            dst[lane + 64] = z;
        }
    }
}

// ---------------- Kernel 2: two-phase GEMM + fused span-scatter epilogue ------
// Phase 1: block streams its 64-row A-panel SEQUENTIALLY (DRAM-page-perfect),
// converts to bf16, stores swizzle-tiled panel to Abf (L2/L3-hot).
//   Tile layout: Abf[panel m0][tile s][rr*64 + pos*8 + e], pos = cc ^ (rr&7),
//   holds A[m0+rr][s*64 + cc*8 + e].
// Phase 2: 16 K-steps; BOTH operands staged by global_load_lds (2 A + 8 B
// gl_lds per wave per step), triple-buffered with LITERAL buffer indices
// (unroll-3), one s_barrier + one counted vmcnt(10) per step (T3/T4; never
// drain to 0 mid-loop). No register A-path in the loop at all.
__global__ __launch_bounds__(256, 1) void gemm_kernel(const float*  __restrict__ A,
                                                      const __bf16* __restrict__ WT,
                                                      const float*  __restrict__ bias,
                                                      const int*    __restrict__ cnt,
                                                      const int*    __restrict__ bucket,
                                                      __bf16*       __restrict__ Abf,
                                                      float*        __restrict__ out) {
    // As: 3 x 8 KB, Bs: 3 x 32 KB -> 120 KB
    __shared__ __align__(16) char smem[3 * BM * BK * 2 + 3 * BN * BK * 2];
    __shared__ int s_cnt[64];
    __shared__ int s_off[65];
    __shared__ int elist[64 * CAP];

    const int tid = threadIdx.x;
    const int w   = tid >> 6;
    const int l   = tid & 63;
    const int lm  = l & 15;
    const int q   = l >> 4;

    const int m0 = blockIdx.x * BM;

    auto bufA = [&](int buf) -> __bf16* { return (__bf16*)smem + buf * (BM * BK); };
    auto bufB = [&](int buf) -> __bf16* { return (__bf16*)(smem + 3 * BM * BK * 2) + buf * (BN * BK); };

    // ---- phase 1: sequential A-panel read -> swizzle-tiled bf16 store -------
    {
        const float* src = A   + (size_t)m0 * D_DIM;
        __bf16*      dst = Abf + (size_t)m0 * D_DIM;
        #pragma unroll 4
        for (int it = 0; it < 32; ++it) {
            const int f  = it * 2048 + tid * 8;   // flat f32 index in panel
            const int rr = f >> 10;               // row 0..63
            const int k  = f & 1023;
            const float4 x0 = *(const float4*)(src + f);
            const float4 x1 = *(const float4*)(src + f + 4);
            bf16x8 v;
            v[0] = (__bf16)x0.x; v[1] = (__bf16)x0.y; v[2] = (__bf16)x0.z; v[3] = (__bf16)x0.w;
            v[4] = (__bf16)x1.x; v[5] = (__bf16)x1.y; v[6] = (__bf16)x1.z; v[7] = (__bf16)x1.w;
            const int c   = k >> 3;               // chunk 0..127
            const int kt  = c >> 3;               // k-tile 0..15
            const int pos = (c & 7) ^ (rr & 7);   // swizzled slot
            *(bf16x8*)(dst + kt * 4096 + rr * 64 + pos * 8) = v;
        }
    }
    asm volatile("s_waitcnt vmcnt(0)");           // stores visible in L2
    __builtin_amdgcn_s_barrier();
    __builtin_amdgcn_sched_barrier(0);

    // ---- phase 2 staging ----------------------------------------------------
    const __bf16* Ap = Abf + (size_t)m0 * D_DIM;  // tiled panel base

    auto stageA = [&](int buf, int s) {           // 2 gl_lds per wave
        __bf16* dA = bufA(buf);
        #pragma unroll
        for (int u = 0; u < 2; ++u) {
            const int jj = w * 2 + u;
            async16(Ap + s * 4096 + jj * 512 + l * 8, dA + jj * 512);
        }
    };

    const int brow_l = l >> 3;
    const int bc     = (l & 7) ^ (brow_l & 7);
    auto stageB = [&](int buf, int s) {           // 8 gl_lds per wave
        __bf16* B = bufB(buf);
        #pragma unroll
        for (int j = 0; j < 8; ++j) {
            const int r   = w * 8 + j;
            const int row = r * 8 + brow_l;
            async16(WT + (size_t)row * D_DIM + s * BK + bc * 8, B + r * 512);
        }
    };

    f32x4 acc[4][4] = {};

    auto compute = [&](int buf) {
        const __bf16* Ab = bufA(buf);
        const __bf16* Bb = bufB(buf);
        #pragma unroll
        for (int kh = 0; kh < 2; ++kh) {
            const int pos = ((kh * 4 + q) ^ (lm & 7)) * 8;
            bf16x8 af[4], bfr[4];
            #pragma unroll
            for (int mi = 0; mi < 4; ++mi)
                af[mi] = *(const bf16x8*)(Ab + (mi * 16 + lm) * BK + pos);
            #pragma unroll
            for (int ni = 0; ni < 4; ++ni)
                bfr[ni] = *(const bf16x8*)(Bb + (w * 64 + ni * 16 + lm) * BK + pos);
            #pragma unroll
            for (int mi = 0; mi < 4; ++mi)
                #pragma unroll
                for (int ni = 0; ni < 4; ++ni)
                    acc[mi][ni] = __builtin_amdgcn_mfma_f32_16x16x32_bf16(
                        af[mi], bfr[ni], acc[mi][ni], 0, 0, 0);
        }
    };

    // ---- prologue: steps 0 and 1 in flight (10 gl_lds per wave each) --------
    stageA(0, 0); stageB(0, 0);
    stageA(1, 1); stageB(1, 1);

    // Per-step: wait own stage(s) (10 ops after it = stage(s+1)), barrier
    // (collective guarantee), issue stage(s+2), compute(s).
#define STEP(s, bcur, bnext, dostage)                          \
    asm volatile("s_waitcnt vmcnt(10)");                       \
    __builtin_amdgcn_sched_barrier(0);                         \
    __builtin_amdgcn_s_barrier();                              \
    __builtin_amdgcn_sched_barrier(0);                         \
    if (dostage) { stageA(bnext, (s) + 2); stageB(bnext, (s) + 2); } \
    __builtin_amdgcn_sched_barrier(0);                         \
    compute(bcur);                                             \
    __builtin_amdgcn_sched_barrier(0);

    #pragma unroll 1
    for (int j = 0; j < 4; ++j) {       // steps 0..11
        const int s0 = j * 3;
        STEP(s0,     0, 2, 1)
        STEP(s0 + 1, 1, 0, 1)
        STEP(s0 + 2, 2, 1, 1)
    }
    STEP(12, 0, 2, 1)                   // stages 14 -> buf2
    STEP(13, 1, 0, 1)                   // stages 15 -> buf0
    STEP(14, 2, 1, 0)                   // no stage; vmcnt(10) = stage(15) after stage(14)
    // step 15: final drain
    asm volatile("s_waitcnt vmcnt(0)");
    __builtin_amdgcn_sched_barrier(0);
    __builtin_amdgcn_s_barrier();
    __builtin_amdgcn_sched_barrier(0);
    compute(0);
#undef STEP

    // ---- fused epilogue ------------------------------------------------------
    __syncthreads();                       // all waves done with As/Bs
    float* hs = (float*)smem;              // 64 x HS f32 overlay (66.6 KB < 120 KB)

    if (tid < 64) { int c = cnt[m0 + tid]; s_cnt[tid] = c < CAP ? c : CAP; }

    // D layout: row = mi*16 + q*4 + r, col = w*64 + ni*16 + lm
    #pragma unroll
    for (int ni = 0; ni < 4; ++ni) {
        const int col = w * 64 + ni * 16 + lm;
        const float bv = bias[col];
        #pragma unroll
        for (int mi = 0; mi < 4; ++mi) {
            const int rbase = mi * 16 + q * 4;
            #pragma unroll
            for (int r = 0; r < 4; ++r)
                hs[(rbase + r) * HS + col] = acc[mi][ni][r] + bv;
        }
    }
    __syncthreads();
    if (tid == 0) {
        int a = 0;
        #pragma unroll 1
        for (int i = 0; i < 64; ++i) { s_off[i] = a; a += s_cnt[i]; }
        s_off[64] = a;
    }
    __syncthreads();
    if (tid < 64) {
        const int o = s_off[tid], c = s_cnt[tid];
        const int* bk = bucket + (size_t)(m0 + tid) * CAP;
        for (int k = 0; k < c; ++k)
            elist[o + k] = (tid << 15) | (bk[k] & 0x7fff);
    }
    __syncthreads();

    const int E   = s_off[64];
    const int grp = tid >> 6;
    const int gl  = tid & 63;
    #pragma unroll 1
    for (int j = grp; j < E; j += 4) {
        const int ent  = elist[j];
        const int rl   = ent >> 15;
        const int code = ent & 0x7fff;
        const int qq   = code >> 2;
        const int st   = (code >> 1) & 1;
        const int hf   = code & 1;
        const float4 v = *(const float4*)&hs[rl * HS + gl * 4];
        *(float4*)(out + (size_t)st * (NQ_ * 512) + (size_t)qq * 512 + hf * 256 + gl * 4) = v;
    }
}

// ---------------- launch ------------------------------------------------------
extern "C" void kernel_launch(void* const* d_in, const int* in_sizes, int n_in,
                              void* d_out, int out_size, void* d_ws, size_t ws_size,
                              hipStream_t stream) {
    const float* A    = (const float*)d_in[1];
    const int*   s1   = (const int*)  d_in[2];
    const int*   e1   = (const int*)  d_in[3];
    const int*   qb   = (const int*)  d_in[4];
    const int*   s2   = (const int*)  d_in[5];
    const int*   e2   = (const int*)  d_in[6];
    const float* W    = (const float*)d_in[7];
    const float* bias = (const float*)d_in[8];
    float*       out  = (float*)d_out;

    __bf16* WT     = (__bf16*)d_ws;                                   // 512 KB
    int*    cnt    = (int*)((char*)d_ws + (1 << 20));                 // 64 KB
    int*    bucket = (int*)((char*)d_ws + (1 << 20) + (1 << 16));     // 2 MB
    __bf16* Abf    = (__bf16*)((char*)d_ws + (16 << 20));             // 32 MB

    wt_kernel  <<<dim3(32, 8), dim3(32, 32), 0, stream>>>(W, WT, cnt);
    index_zero <<<dim3(NQ_ / 256), dim3(256), 0, stream>>>(s1, e1, s2, e2, qb, cnt, bucket, out);
    gemm_kernel<<<dim3(M_TOT / BM), dim3(256), 0, stream>>>(A, WT, bias, cnt, bucket, Abf, out);
}

// Round 5
// 154.119 us; speedup vs baseline: 1.0039x; 1.0039x over previous
//
#include <hip/hip_runtime.h>
#include <hip/hip_bf16.h>
#include <stdint.h>

#define S_LEN 2048
#define D_DIM 1024
#define P_DIM 256
#define NQ_   8192
#define M_TOT 16384  // B*S
#define CAP 32       // max span-endpoints per H row (lambda=2, P(>32)~1e-26)
#define HS  260      // padded f32 row stride for H tile in LDS

typedef __attribute__((ext_vector_type(4))) float  f32x4;
typedef __attribute__((ext_vector_type(8))) __bf16 bf16x8;

// ============================================================================
// Fragment layouts (lane l = q*16+lm, q=l>>4, lm=l&15):
//   Afrag[r16][t][kh] : 1-KB block; lane l elem e = A[r16*16+lm][t*64+(kh*4+q)*8+e]
//     elem offset = (r16*32 + t*2 + kh)*512 + l*8
//   WTf[c16][t][kh]   : 1-KB block; lane l elem e = W[t*64+(kh*4+q)*8+e][c16*16+lm]
//     elem offset = (c16*32 + t*2 + kh)*512 + l*8
// These reproduce EXACTLY the operands the verified LDS-staged kernel fed to
// mfma_f32_16x16x32_bf16 (XOR store/read swizzle cancels), so results are
// bit-identical.
// ============================================================================

// ---------------- Kernel 0: W [1024][256] f32 -> WTf (fragment order) ---------
// Also zeroes the 16384-entry row-bucket counters.
__global__ __launch_bounds__(1024) void wtf_kernel(const float* __restrict__ W,
                                                   __bf16* __restrict__ WTf,
                                                   int* __restrict__ cnt) {
    __shared__ float tile[32][33];
    const int bx = blockIdx.x;            // k0 = bx*32  -> (t = bx>>1, kh = bx&1)
    const int by = blockIdx.y;            // n0 = by*32  -> c16 in {2by, 2by+1}
    const int k0 = bx * 32, n0 = by * 32;
    const int tx = threadIdx.x, ty = threadIdx.y;
    const int g = (by * 32 + bx) * 1024 + ty * 32 + tx;
    if (g < M_TOT) cnt[g] = 0;
    tile[ty][tx] = W[(k0 + ty) * P_DIM + (n0 + tx)];   // coalesced
    __syncthreads();
    const int t = ty * 32 + tx;
    if (t < 128) {                        // 2 c16r * 4 q * 16 lm writers
        const int c16r = t >> 6, q = (t >> 4) & 3, lm = t & 15;
        bf16x8 v;
        #pragma unroll
        for (int e = 0; e < 8; ++e) v[e] = (__bf16)tile[q * 8 + e][c16r * 16 + lm];
        const int c16 = by * 2 + c16r;
        const int ts  = bx >> 1, kh = bx & 1;
        *(bf16x8*)(WTf + (size_t)((c16 * 32 + ts * 2 + kh) * 512 + (q * 16 + lm) * 8)) = v;
    }
}

// ---------------- Kernel 1: A [16384][1024] f32 -> Afrag bf16 (streaming) -----
// 1024 blocks x 256 thr, fill-like: block b owns rows b*16..+16 (r16 = b).
// Reads: 512-B contiguous runs per 16-thread group. Writes: each 64-B line of
// a fragment is fully covered by 4 lanes of the same wave -> coalesced.
__global__ __launch_bounds__(256) void a_cvt(const float* __restrict__ A,
                                             __bf16* __restrict__ Af) {
    const int b  = blockIdx.x;
    const int t  = threadIdx.x;
    const int rr = t >> 4;                 // row 0..15 within strip
    const int cq = t & 15;
    const float* src = A  + (size_t)(b * 16 + rr) * D_DIM;
    __bf16*      dst = Af + (size_t)b * 16384;
    #pragma unroll
    for (int it = 0; it < 8; ++it) {
        const int c = it * 16 + cq;        // 8-elem chunk 0..127
        const float4 x0 = *(const float4*)(src + c * 8);
        const float4 x1 = *(const float4*)(src + c * 8 + 4);
        bf16x8 v;
        v[0] = (__bf16)x0.x; v[1] = (__bf16)x0.y; v[2] = (__bf16)x0.z; v[3] = (__bf16)x0.w;
        v[4] = (__bf16)x1.x; v[5] = (__bf16)x1.y; v[6] = (__bf16)x1.z; v[7] = (__bf16)x1.w;
        const int ts = c >> 3, kh = (c >> 2) & 1, qp = c & 3;
        *(bf16x8*)(dst + (ts * 2 + kh) * 512 + (qp * 16 + rr) * 8) = v;
    }
}

// ---------------- Kernel 2: inverted span index + invalid-span zeroing --------
__global__ __launch_bounds__(256) void index_zero(const int* __restrict__ s1,
                                                  const int* __restrict__ e1,
                                                  const int* __restrict__ s2,
                                                  const int* __restrict__ e2,
                                                  const int* __restrict__ qb,
                                                  int* __restrict__ cnt,
                                                  int* __restrict__ bucket,
                                                  float* __restrict__ out) {
    const int q    = blockIdx.x * 256 + threadIdx.x;
    const int lane = threadIdx.x & 63;
    const int bqw  = blockIdx.x * 256 + (threadIdx.x & ~63);  // wave's first q
    const int b    = qb[q];
    const float4 z = make_float4(0.f, 0.f, 0.f, 0.f);
    #pragma unroll
    for (int set = 0; set < 2; ++set) {
        const int s = set ? s2[q] : s1[q];
        const int e = set ? e2[q] : e1[q];
        if (e >= s) {
            int r = b * S_LEN + s;
            int k = atomicAdd(&cnt[r], 1); if (k < CAP) bucket[r * CAP + k] = (q << 2) | (set << 1);
            r = b * S_LEN + e;
            k = atomicAdd(&cnt[r], 1);     if (k < CAP) bucket[r * CAP + k] = (q << 2) | (set << 1) | 1;
        }
        unsigned long long mask = __ballot(e < s);
        while (mask) {
            const int j = __ffsll(mask) - 1;
            mask &= mask - 1;
            const int qz = bqw + j;
            float4* dst = (float4*)(out + (size_t)set * (NQ_ * 512) + (size_t)qz * 512);
            dst[lane]      = z;
            dst[lane + 64] = z;
        }
    }
}

// ---------------- Kernel 3: fragment-direct GEMM + span-scatter epilogue ------
// 512 blocks x 256 thr (2 blocks/CU, 2 waves/SIMD). Block owns 32 rows; wave w
// owns cols [w*64,+64). NO LDS staging, NO barriers, NO gl_lds in the K-loop:
// each step is 12 perfectly-coalesced 1-KB fragment loads (A from L3/L1-shared
// Afrag, B from L2-resident WTf) + 16 MFMAs, register double-buffered with
// literal buffer indices (rule #20: all array indices compile-time).
__global__ __launch_bounds__(256, 2) void gemm_kernel(const __bf16* __restrict__ Af,
                                                      const __bf16* __restrict__ WTf,
                                                      const float*  __restrict__ bias,
                                                      const int*    __restrict__ cnt,
                                                      const int*    __restrict__ bucket,
                                                      float*        __restrict__ out) {
    __shared__ float hs[32 * HS];
    __shared__ int s_cnt[32];
    __shared__ int s_off[33];
    __shared__ int elist[32 * CAP];

    const int tid = threadIdx.x;
    const int w   = tid >> 6;
    const int l   = tid & 63;
    const int lm  = l & 15;
    const int q   = l >> 4;

    const int m0  = blockIdx.x * 32;
    const int r16 = blockIdx.x * 2;

    // Per-(mi,kh) / per-(ni,kh) fragment base pointers; step t adds t*1024 elems.
    const __bf16* apb[2][2];
    const __bf16* bpb[4][2];
    #pragma unroll
    for (int mi = 0; mi < 2; ++mi)
        #pragma unroll
        for (int kh = 0; kh < 2; ++kh)
            apb[mi][kh] = Af + (size_t)(((r16 + mi) * 32 + kh) * 512 + l * 8);
    #pragma unroll
    for (int ni = 0; ni < 4; ++ni)
        #pragma unroll
        for (int kh = 0; kh < 2; ++kh)
            bpb[ni][kh] = WTf + (size_t)(((w * 4 + ni) * 32 + kh) * 512 + l * 8);

    bf16x8 a_[2][2][2];   // [buf][mi][kh]
    bf16x8 b_[2][4][2];   // [buf][ni][kh]
    f32x4  acc[2][4] = {};

#define LOADSTEP(B, T)                                                        \
    _Pragma("unroll") for (int mi = 0; mi < 2; ++mi)                          \
        _Pragma("unroll") for (int kh = 0; kh < 2; ++kh)                      \
            a_[B][mi][kh] = *(const bf16x8*)(apb[mi][kh] + (T) * 1024);       \
    _Pragma("unroll") for (int ni = 0; ni < 4; ++ni)                          \
        _Pragma("unroll") for (int kh = 0; kh < 2; ++kh)                      \
            b_[B][ni][kh] = *(const bf16x8*)(bpb[ni][kh] + (T) * 1024);

#define MMASTEP(B)                                                            \
    _Pragma("unroll") for (int kh = 0; kh < 2; ++kh)                          \
        _Pragma("unroll") for (int mi = 0; mi < 2; ++mi)                      \
            _Pragma("unroll") for (int ni = 0; ni < 4; ++ni)                  \
                acc[mi][ni] = __builtin_amdgcn_mfma_f32_16x16x32_bf16(        \
                    a_[B][mi][kh], b_[B][ni][kh], acc[mi][ni], 0, 0, 0);

    LOADSTEP(0, 0)
    #pragma unroll 1
    for (int t = 0; t < 14; t += 2) {
        LOADSTEP(1, t + 1)
        MMASTEP(0)
        LOADSTEP(0, t + 2)
        MMASTEP(1)
    }
    LOADSTEP(1, 15)
    MMASTEP(0)
    MMASTEP(1)
#undef LOADSTEP
#undef MMASTEP

    // ---- fused epilogue: stage 32x256 tile (+bias) in LDS, scatter spans ----
    if (tid < 32) { int c = cnt[m0 + tid]; s_cnt[tid] = c < CAP ? c : CAP; }

    // D layout: row = mi*16 + q*4 + r, col = w*64 + ni*16 + lm
    #pragma unroll
    for (int ni = 0; ni < 4; ++ni) {
        const int col = w * 64 + ni * 16 + lm;
        const float bv = bias[col];
        #pragma unroll
        for (int mi = 0; mi < 2; ++mi) {
            const int rbase = mi * 16 + q * 4;
            #pragma unroll
            for (int r = 0; r < 4; ++r)
                hs[(rbase + r) * HS + col] = acc[mi][ni][r] + bv;
        }
    }
    __syncthreads();
    if (tid == 0) {
        int a = 0;
        #pragma unroll 1
        for (int i = 0; i < 32; ++i) { s_off[i] = a; a += s_cnt[i]; }
        s_off[32] = a;
    }
    __syncthreads();
    if (tid < 32) {
        const int o = s_off[tid], c = s_cnt[tid];
        const int* bk = bucket + (size_t)(m0 + tid) * CAP;
        for (int k = 0; k < c; ++k)
            elist[o + k] = (tid << 15) | (bk[k] & 0x7fff);
    }
    __syncthreads();

    const int E   = s_off[32];
    const int grp = tid >> 6;
    const int gl  = tid & 63;
    #pragma unroll 1
    for (int j = grp; j < E; j += 4) {
        const int ent  = elist[j];
        const int rl   = ent >> 15;
        const int code = ent & 0x7fff;
        const int qq   = code >> 2;
        const int st   = (code >> 1) & 1;
        const int hf   = code & 1;
        const float4 v = *(const float4*)&hs[rl * HS + gl * 4];
        *(float4*)(out + (size_t)st * (NQ_ * 512) + (size_t)qq * 512 + hf * 256 + gl * 4) = v;
    }
}

// ---------------- launch ------------------------------------------------------
extern "C" void kernel_launch(void* const* d_in, const int* in_sizes, int n_in,
                              void* d_out, int out_size, void* d_ws, size_t ws_size,
                              hipStream_t stream) {
    const float* A    = (const float*)d_in[1];
    const int*   s1   = (const int*)  d_in[2];
    const int*   e1   = (const int*)  d_in[3];
    const int*   qb   = (const int*)  d_in[4];
    const int*   s2   = (const int*)  d_in[5];
    const int*   e2   = (const int*)  d_in[6];
    const float* W    = (const float*)d_in[7];
    const float* bias = (const float*)d_in[8];
    float*       out  = (float*)d_out;

    __bf16* WTf    = (__bf16*)d_ws;                                   // 512 KB
    int*    cnt    = (int*)((char*)d_ws + (1 << 20));                 // 64 KB
    int*    bucket = (int*)((char*)d_ws + (1 << 20) + (1 << 16));     // 2 MB
    __bf16* Af     = (__bf16*)((char*)d_ws + (16 << 20));             // 32 MB

    a_cvt      <<<dim3(1024), dim3(256), 0, stream>>>(A, Af);
    wtf_kernel <<<dim3(32, 8), dim3(32, 32), 0, stream>>>(W, WTf, cnt);
    index_zero <<<dim3(NQ_ / 256), dim3(256), 0, stream>>>(s1, e1, s2, e2, qb, cnt, bucket, out);
    gemm_kernel<<<dim3(M_TOT / 32), dim3(256), 0, stream>>>(Af, WTf, bias, cnt, bucket, out);
}

// Round 6
// 135.905 us; speedup vs baseline: 1.1384x; 1.1340x over previous
//
#include <hip/hip_runtime.h>
#include <hip/hip_bf16.h>
#include <stdint.h>

#define S_LEN 2048
#define D_DIM 1024
#define P_DIM 256
#define NQ_   8192
#define M_TOT 16384  // B*S
#define CAP 32       // max span-endpoints per H row
#define HS  260      // padded f32 row stride for H tile in LDS

typedef __attribute__((ext_vector_type(4))) float  f32x4;
typedef __attribute__((ext_vector_type(8))) __bf16 bf16x8;

// ============================================================================
// Fragment spec (verified on harness, lane l = q*16+lm):
//   A-frag(mi,kt,kh): lane l elem e = A[m0+mi*16+lm][kt*64+(kh*4+q)*8+e]
//   B-frag(c16,kt,kh) in WTf at (c16*32+kt*2+kh)*512 + l*8:
//                     lane l elem e = W[kt*64+(kh*4+q)*8+e][c16*16+lm]
// A-frags live in LDS with bank swizzle slot=lm^(q<<1) applied at BOTH write
// and read (write 2-way, read 2-way bank aliasing = free per m136).
// ============================================================================

// ---------------- Kernel 0: W [1024][256] f32 -> WTf (fragment order) ---------
// Also zeroes the 16384-entry row-bucket counters.
__global__ __launch_bounds__(1024) void wtf_kernel(const float* __restrict__ W,
                                                   __bf16* __restrict__ WTf,
                                                   int* __restrict__ cnt) {
    __shared__ float tile[32][33];
    const int bx = blockIdx.x;            // k0 = bx*32 -> (kt = bx>>1, kh = bx&1)
    const int by = blockIdx.y;            // n0 = by*32 -> c16 in {2by, 2by+1}
    const int k0 = bx * 32, n0 = by * 32;
    const int tx = threadIdx.x, ty = threadIdx.y;
    const int g = (by * 32 + bx) * 1024 + ty * 32 + tx;
    if (g < M_TOT) cnt[g] = 0;
    tile[ty][tx] = W[(k0 + ty) * P_DIM + (n0 + tx)];   // coalesced
    __syncthreads();
    const int t = ty * 32 + tx;
    if (t < 128) {                        // 2 c16r * 4 q * 16 lm writers
        const int c16r = t >> 6, q = (t >> 4) & 3, lm = t & 15;
        bf16x8 v;
        #pragma unroll
        for (int e = 0; e < 8; ++e) v[e] = (__bf16)tile[q * 8 + e][c16r * 16 + lm];
        const int c16 = by * 2 + c16r;
        const int ts  = bx >> 1, kh = bx & 1;
        *(bf16x8*)(WTf + (size_t)((c16 * 32 + ts * 2 + kh) * 512 + (q * 16 + lm) * 8)) = v;
    }
}

// ---------------- Kernel 1: inverted span index + invalid-span zeroing --------
// 128 blocks x 256 thr: wave = (set, half) x 64 q. half==0 waves do atomics;
// every wave ballot-zeroes its 1 KB half of each invalid span.
__global__ __launch_bounds__(256) void index_zero(const int* __restrict__ s1,
                                                  const int* __restrict__ e1,
                                                  const int* __restrict__ s2,
                                                  const int* __restrict__ e2,
                                                  const int* __restrict__ qb,
                                                  int* __restrict__ cnt,
                                                  int* __restrict__ bucket,
                                                  float* __restrict__ out) {
    const int lane = threadIdx.x & 63;
    const int q    = blockIdx.x * 64 + lane;
    const int set  = threadIdx.x >> 7;
    const int half = (threadIdx.x >> 6) & 1;
    const int b    = qb[q];
    const int s = set ? s2[q] : s1[q];
    const int e = set ? e2[q] : e1[q];
    if (!half && e >= s) {
        int r = b * S_LEN + s;
        int k = atomicAdd(&cnt[r], 1); if (k < CAP) bucket[r * CAP + k] = (q << 2) | (set << 1);
        r = b * S_LEN + e;
        k = atomicAdd(&cnt[r], 1);     if (k < CAP) bucket[r * CAP + k] = (q << 2) | (set << 1) | 1;
    }
    unsigned long long mask = __ballot(e < s);
    const int bqw = blockIdx.x * 64;
    const float4 z = make_float4(0.f, 0.f, 0.f, 0.f);
    while (mask) {
        const int j = __ffsll(mask) - 1;
        mask &= mask - 1;
        float* dst = out + (size_t)set * (NQ_ * 512) + (size_t)(bqw + j) * 512 + half * 256;
        ((float4*)dst)[lane] = z;
    }
}

// ---------------- Kernel 2: fused cvt + fragment GEMM + span scatter ----------
// 512 blocks x 256 thr (2 blocks/CU). Phase 1: block streams its own 128 KB
// A-panel (coalesced 256-B segments), cvt to bf16, ds_write in fragment order
// (swizzled). ONE barrier. Phase 2: barrier-free K-loop, per-block phase
// stagger kt=(t+5*blk)&15 de-convoys the shared WTf sweep; per step 4
// ds_read_b128 (A) + 8 direct 1-KB B loads (3-buffer regs, distance 2,
// literal indices) + 16 MFMAs. Epilogue: verified span scatter, hs overlays
// the A-panel LDS after a barrier.
__global__ __launch_bounds__(256, 2) void gemm_kernel(const float*  __restrict__ A,
                                                      const __bf16* __restrict__ WTf,
                                                      const float*  __restrict__ bias,
                                                      const int*    __restrict__ cnt,
                                                      const int*    __restrict__ bucket,
                                                      float*        __restrict__ out) {
    __shared__ __align__(16) __bf16 Afl[32768];   // 64 KB A-panel fragments
    __shared__ int s_cnt[32];
    __shared__ int s_off[33];
    __shared__ int elist[32 * CAP];

    const int tid = threadIdx.x;
    const int w   = tid >> 6;
    const int l   = tid & 63;
    const int lm  = l & 15;
    const int q   = l >> 4;

    const int m0 = blockIdx.x * 32;
    const int ph = (blockIdx.x * 5) & 15;          // K-phase stagger (5⊥16)

    // ---- phase 1: A panel -> LDS fragments ----------------------------------
    {
        const int r   = tid >> 3;                  // row 0..31
        const int la  = tid & 7;
        const int mi  = r >> 4, lmr = r & 15;
        const float* src = A + (size_t)(m0 + r) * D_DIM;
        #pragma unroll
        for (int it = 0; it < 16; ++it) {
            const int c = it * 8 + la;             // 8-elem chunk 0..127
            const float4 x0 = *(const float4*)(src + c * 8);
            const float4 x1 = *(const float4*)(src + c * 8 + 4);
            bf16x8 v;
            v[0] = (__bf16)x0.x; v[1] = (__bf16)x0.y; v[2] = (__bf16)x0.z; v[3] = (__bf16)x0.w;
            v[4] = (__bf16)x1.x; v[5] = (__bf16)x1.y; v[6] = (__bf16)x1.z; v[7] = (__bf16)x1.w;
            const int kt = c >> 3, kh = (c >> 2) & 1, qp = c & 3;
            const int slot = lmr ^ (qp << 1);      // bank swizzle
            *(bf16x8*)(&Afl[(mi * 32 + kt * 2 + kh) * 512 + qp * 128 + slot * 8]) = v;
        }
    }
    __syncthreads();

    // ---- phase 2: barrier-free K-loop ---------------------------------------
    const int slotr = lm ^ (q << 1);
    const __bf16* abase = Afl + q * 128 + slotr * 8;     // + (mi*32+kt*2+kh)*512
    const __bf16* bp[4][2];
    #pragma unroll
    for (int ni = 0; ni < 4; ++ni)
        #pragma unroll
        for (int kh = 0; kh < 2; ++kh)
            bp[ni][kh] = WTf + (size_t)(((w * 4 + ni) * 32 + kh) * 512 + l * 8);

    bf16x8 bre[3][4][2];                     // [buf][ni][kh], literal indices only
    f32x4  acc[2][4] = {};

#define LOADB(B, T) {                                                         \
    const int kt_ = ((T) + ph) & 15;                                          \
    _Pragma("unroll") for (int ni = 0; ni < 4; ++ni)                          \
        _Pragma("unroll") for (int kh = 0; kh < 2; ++kh)                      \
            bre[B][ni][kh] = *(const bf16x8*)(bp[ni][kh] + kt_ * 1024); }

    LOADB(0, 0)
    LOADB(1, 1)
    #pragma unroll
    for (int t = 0; t < 16; ++t) {
        if (t < 14) LOADB((t + 2) % 3, t + 2)           // safe: != t%3, (t+1)%3
        const int kt_ = (t + ph) & 15;
        bf16x8 af[2][2];
        #pragma unroll
        for (int mi = 0; mi < 2; ++mi)
            #pragma unroll
            for (int kh = 0; kh < 2; ++kh)
                af[mi][kh] = *(const bf16x8*)(abase + (mi * 32 + kt_ * 2 + kh) * 512);
        #pragma unroll
        for (int kh = 0; kh < 2; ++kh)
            #pragma unroll
            for (int mi = 0; mi < 2; ++mi)
                #pragma unroll
                for (int ni = 0; ni < 4; ++ni)
                    acc[mi][ni] = __builtin_amdgcn_mfma_f32_16x16x32_bf16(
                        af[mi][kh], bre[t % 3][ni][kh], acc[mi][ni], 0, 0, 0);
    }
#undef LOADB

    // ---- fused epilogue (hs overlays Afl; barrier first) --------------------
    __syncthreads();                       // all waves done reading Afl
    float* hs = (float*)Afl;               // 32 x HS f32 = 33.3 KB < 64 KB

    if (tid < 32) { int c = cnt[m0 + tid]; s_cnt[tid] = c < CAP ? c : CAP; }

    // D layout: row = mi*16 + q*4 + r, col = w*64 + ni*16 + lm
    #pragma unroll
    for (int ni = 0; ni < 4; ++ni) {
        const int col = w * 64 + ni * 16 + lm;
        const float bv = bias[col];
        #pragma unroll
        for (int mi = 0; mi < 2; ++mi) {
            const int rbase = mi * 16 + q * 4;
            #pragma unroll
            for (int r = 0; r < 4; ++r)
                hs[(rbase + r) * HS + col] = acc[mi][ni][r] + bv;
        }
    }
    __syncthreads();
    if (tid == 0) {
        int a = 0;
        #pragma unroll 1
        for (int i = 0; i < 32; ++i) { s_off[i] = a; a += s_cnt[i]; }
        s_off[32] = a;
    }
    __syncthreads();
    if (tid < 32) {
        const int o = s_off[tid], c = s_cnt[tid];
        const int* bk = bucket + (size_t)(m0 + tid) * CAP;
        for (int k = 0; k < c; ++k)
            elist[o + k] = (tid << 15) | (bk[k] & 0x7fff);
    }
    __syncthreads();

    const int E   = s_off[32];
    const int grp = tid >> 6;
    const int gl  = tid & 63;
    #pragma unroll 1
    for (int j = grp; j < E; j += 4) {
        const int ent  = elist[j];
        const int rl   = ent >> 15;
        const int code = ent & 0x7fff;
        const int qq   = code >> 2;
        const int st   = (code >> 1) & 1;
        const int hf   = code & 1;
        const float4 v = *(const float4*)&hs[rl * HS + gl * 4];
        *(float4*)(out + (size_t)st * (NQ_ * 512) + (size_t)qq * 512 + hf * 256 + gl * 4) = v;
    }
}

// ---------------- launch ------------------------------------------------------
extern "C" void kernel_launch(void* const* d_in, const int* in_sizes, int n_in,
                              void* d_out, int out_size, void* d_ws, size_t ws_size,
                              hipStream_t stream) {
    const float* A    = (const float*)d_in[1];
    const int*   s1   = (const int*)  d_in[2];
    const int*   e1   = (const int*)  d_in[3];
    const int*   qb   = (const int*)  d_in[4];
    const int*   s2   = (const int*)  d_in[5];
    const int*   e2   = (const int*)  d_in[6];
    const float* W    = (const float*)d_in[7];
    const float* bias = (const float*)d_in[8];
    float*       out  = (float*)d_out;

    __bf16* WTf    = (__bf16*)d_ws;                                   // 512 KB
    int*    cnt    = (int*)((char*)d_ws + (1 << 20));                 // 64 KB
    int*    bucket = (int*)((char*)d_ws + (1 << 20) + (1 << 16));     // 2 MB

    wtf_kernel <<<dim3(32, 8), dim3(32, 32), 0, stream>>>(W, WTf, cnt);
    index_zero <<<dim3(NQ_ / 64), dim3(256), 0, stream>>>(s1, e1, s2, e2, qb, cnt, bucket, out);
    gemm_kernel<<<dim3(M_TOT / 32), dim3(256), 0, stream>>>(A, WTf, bias, cnt, bucket, out);
}

// Round 8
// 133.905 us; speedup vs baseline: 1.1554x; 1.0149x over previous
//
#include <hip/hip_runtime.h>
#include <hip/hip_bf16.h>
#include <stdint.h>

#define S_LEN 2048
#define D_DIM 1024
#define P_DIM 256
#define NQ_   8192
#define M_TOT 16384  // B*S
#define CAP 32       // max span-endpoints per H row
#define HS  260      // padded f32 row stride for H tile in LDS

typedef __attribute__((ext_vector_type(4))) float  f32x4;
typedef __attribute__((ext_vector_type(8))) __bf16 bf16x8;

// ============================================================================
// Fragment spec (harness-verified, lane l = q*16+lm):
//   A-frag(mi,kt,kh): lane l elem e = A[m0+mi*16+lm][kt*64+(kh*4+q)*8+e]
//     in LDS at (mi*32+kt*2+kh)*512 + qp*128 + (lm^(qp<<1))*8   (bank swizzle)
//   B-frag(c16,kt,kh) in WTf at (c16*32+kt*2+kh)*512 + l*8:
//     lane l elem e = W[kt*64+(kh*4+q)*8+e][c16*16+lm]
// ============================================================================

// ---------------- Kernel 0: W [1024][256] f32 -> WTf (fragment order) ---------
// Also zeroes the 16384-entry row-bucket counters.
__global__ __launch_bounds__(1024) void wtf_kernel(const float* __restrict__ W,
                                                   __bf16* __restrict__ WTf,
                                                   int* __restrict__ cnt) {
    __shared__ float tile[32][33];
    const int bx = blockIdx.x;            // k0 = bx*32 -> (kt = bx>>1, kh = bx&1)
    const int by = blockIdx.y;            // n0 = by*32 -> c16 in {2by, 2by+1}
    const int k0 = bx * 32, n0 = by * 32;
    const int tx = threadIdx.x, ty = threadIdx.y;
    const int g = (by * 32 + bx) * 1024 + ty * 32 + tx;
    if (g < M_TOT) cnt[g] = 0;
    tile[ty][tx] = W[(k0 + ty) * P_DIM + (n0 + tx)];   // coalesced
    __syncthreads();
    const int t = ty * 32 + tx;
    if (t < 128) {                        // 2 c16r * 4 q * 16 lm writers
        const int c16r = t >> 6, q = (t >> 4) & 3, lm = t & 15;
        bf16x8 v;
        #pragma unroll
        for (int e = 0; e < 8; ++e) v[e] = (__bf16)tile[q * 8 + e][c16r * 16 + lm];
        const int c16 = by * 2 + c16r;
        const int ts  = bx >> 1, kh = bx & 1;
        *(bf16x8*)(WTf + (size_t)((c16 * 32 + ts * 2 + kh) * 512 + (q * 16 + lm) * 8)) = v;
    }
}

// ---------------- Kernel 1: inverted span index + invalid-span zeroing --------
__global__ __launch_bounds__(256) void index_zero(const int* __restrict__ s1,
                                                  const int* __restrict__ e1,
                                                  const int* __restrict__ s2,
                                                  const int* __restrict__ e2,
                                                  const int* __restrict__ qb,
                                                  int* __restrict__ cnt,
                                                  int* __restrict__ bucket,
                                                  float* __restrict__ out) {
    const int lane = threadIdx.x & 63;
    const int q    = blockIdx.x * 64 + lane;
    const int set  = threadIdx.x >> 7;
    const int half = (threadIdx.x >> 6) & 1;
    const int b    = qb[q];
    const int s = set ? s2[q] : s1[q];
    const int e = set ? e2[q] : e1[q];
    if (!half && e >= s) {
        int r = b * S_LEN + s;
        int k = atomicAdd(&cnt[r], 1); if (k < CAP) bucket[r * CAP + k] = (q << 2) | (set << 1);
        r = b * S_LEN + e;
        k = atomicAdd(&cnt[r], 1);     if (k < CAP) bucket[r * CAP + k] = (q << 2) | (set << 1) | 1;
    }
    unsigned long long mask = __ballot(e < s);
    const int bqw = blockIdx.x * 64;
    const float4 z = make_float4(0.f, 0.f, 0.f, 0.f);
    while (mask) {
        const int j = __ffsll(mask) - 1;
        mask &= mask - 1;
        float* dst = out + (size_t)set * (NQ_ * 512) + (size_t)(bqw + j) * 512 + half * 256;
        ((float4*)dst)[lane] = z;
    }
}

// ---------------- Kernel 2: fused cvt + fragment GEMM + span scatter ----------
// 256 blocks x 512 thr (1 block/CU, 2 waves/SIMD). BM=64: wave w owns ALL 64
// rows x cols [w*32,+32) -> per-block WTf sweep amortized over 2x the output
// vs BM=32 (halves total L2 B-traffic to 128 MB). Phase 1: block streams its
// 256 KB A-panel (coalesced), cvt, ds_write in fragment order (swizzled).
// First two B-load rounds issue BEFORE the barrier (depend only on WTf).
// Phase 2: barrier-free K-loop, per-block stagger kt=(t+5*blk)&15; per step
// 8 ds_read_b128 (A) + 4 direct 1-KB B loads (3-buf regs, literal indices)
// + 16 MFMAs. Epilogue: verified span scatter; hs overlays the A-panel LDS.
__global__ __launch_bounds__(512, 1) void gemm_kernel(const float*  __restrict__ A,
                                                      const __bf16* __restrict__ WTf,
                                                      const float*  __restrict__ bias,
                                                      const int*    __restrict__ cnt,
                                                      const int*    __restrict__ bucket,
                                                      float*        __restrict__ out) {
    __shared__ __align__(16) __bf16 Afl[65536];   // 128 KB A-panel fragments
    __shared__ int s_cnt[64];
    __shared__ int s_off[65];
    __shared__ int elist[64 * CAP];

    const int tid = threadIdx.x;
    const int w   = tid >> 6;             // wave 0..7
    const int l   = tid & 63;
    const int lm  = l & 15;
    const int q   = l >> 4;

    const int m0 = blockIdx.x * 64;
    const int ph = (blockIdx.x * 5) & 15;          // K-phase stagger (5⊥16)

    // ---- B fragment pointers + register triple-buffer (literal indices) -----
    const __bf16* bp[2][2];
    #pragma unroll
    for (int ni = 0; ni < 2; ++ni)
        #pragma unroll
        for (int kh = 0; kh < 2; ++kh)
            bp[ni][kh] = WTf + (size_t)(((w * 2 + ni) * 32 + kh) * 512 + l * 8);

    bf16x8 bre[3][2][2];
#define LOADB(B, T) {                                                         \
    const int kt_ = ((T) + ph) & 15;                                          \
    _Pragma("unroll") for (int ni = 0; ni < 2; ++ni)                          \
        _Pragma("unroll") for (int kh = 0; kh < 2; ++kh)                      \
            bre[B][ni][kh] = *(const bf16x8*)(bp[ni][kh] + kt_ * 1024); }

    LOADB(0, 0)                           // issued before phase-1 barrier:
    LOADB(1, 1)                           // L2 latency hides under the sync

    // ---- phase 1: A panel -> LDS fragments ----------------------------------
    {
        const int r   = tid >> 3;                  // row 0..63
        const int la  = tid & 7;
        const int mi  = r >> 4, lmr = r & 15;
        const float* src = A + (size_t)(m0 + r) * D_DIM;
        #pragma unroll
        for (int it = 0; it < 16; ++it) {
            const int c = it * 8 + la;             // 8-elem chunk 0..127
            const float4 x0 = *(const float4*)(src + c * 8);
            const float4 x1 = *(const float4*)(src + c * 8 + 4);
            bf16x8 v;
            v[0] = (__bf16)x0.x; v[1] = (__bf16)x0.y; v[2] = (__bf16)x0.z; v[3] = (__bf16)x0.w;
            v[4] = (__bf16)x1.x; v[5] = (__bf16)x1.y; v[6] = (__bf16)x1.z; v[7] = (__bf16)x1.w;
            const int kt = c >> 3, kh = (c >> 2) & 1, qp = c & 3;
            const int slot = lmr ^ (qp << 1);      // bank swizzle
            *(bf16x8*)(&Afl[(mi * 32 + kt * 2 + kh) * 512 + qp * 128 + slot * 8]) = v;
        }
    }
    __syncthreads();

    // ---- phase 2: barrier-free K-loop ---------------------------------------
    const int slotr = lm ^ (q << 1);
    const __bf16* abase = Afl + q * 128 + slotr * 8;   // + (mi*32+kt*2+kh)*512
    f32x4 acc[4][2] = {};

    #pragma unroll
    for (int t = 0; t < 16; ++t) {
        if (t < 14) LOADB((t + 2) % 3, t + 2)           // safe: != t%3, (t+1)%3
        const int kt_ = (t + ph) & 15;
        bf16x8 af[4][2];
        #pragma unroll
        for (int mi = 0; mi < 4; ++mi)
            #pragma unroll
            for (int kh = 0; kh < 2; ++kh)
                af[mi][kh] = *(const bf16x8*)(abase + (mi * 32 + kt_ * 2 + kh) * 512);
        #pragma unroll
        for (int kh = 0; kh < 2; ++kh)
            #pragma unroll
            for (int mi = 0; mi < 4; ++mi)
                #pragma unroll
                for (int ni = 0; ni < 2; ++ni)
                    acc[mi][ni] = __builtin_amdgcn_mfma_f32_16x16x32_bf16(
                        af[mi][kh], bre[t % 3][ni][kh], acc[mi][ni], 0, 0, 0);
    }
#undef LOADB

    // ---- fused epilogue (hs overlays Afl; barrier first) --------------------
    __syncthreads();                       // all waves done reading Afl
    float* hs = (float*)Afl;               // 64 x HS f32 = 66.6 KB < 128 KB

    if (tid < 64) { int c = cnt[m0 + tid]; s_cnt[tid] = c < CAP ? c : CAP; }

    // D layout: row = mi*16 + q*4 + r, col = w*32 + ni*16 + lm
    #pragma unroll
    for (int ni = 0; ni < 2; ++ni) {
        const int col = w * 32 + ni * 16 + lm;
        const float bv = bias[col];
        #pragma unroll
        for (int mi = 0; mi < 4; ++mi) {
            const int rbase = mi * 16 + q * 4;
            #pragma unroll
            for (int r = 0; r < 4; ++r)
                hs[(rbase + r) * HS + col] = acc[mi][ni][r] + bv;
        }
    }
    __syncthreads();
    if (tid == 0) {
        int a = 0;
        #pragma unroll 1
        for (int i = 0; i < 64; ++i) { s_off[i] = a; a += s_cnt[i]; }
        s_off[64] = a;
    }
    __syncthreads();
    if (tid < 64) {
        const int o = s_off[tid], c = s_cnt[tid];
        const int* bk = bucket + (size_t)(m0 + tid) * CAP;
        for (int k = 0; k < c; ++k)
            elist[o + k] = (tid << 15) | (bk[k] & 0x7fff);
    }
    __syncthreads();

    const int E   = s_off[64];
    const int grp = tid >> 6;
    const int gl  = tid & 63;
    #pragma unroll 1
    for (int j = grp; j < E; j += 8) {
        const int ent  = elist[j];
        const int rl   = ent >> 15;
        const int code = ent & 0x7fff;
        const int qq   = code >> 2;
        const int st   = (code >> 1) & 1;
        const int hf   = code & 1;
        const float4 v = *(const float4*)&hs[rl * HS + gl * 4];
        *(float4*)(out + (size_t)st * (NQ_ * 512) + (size_t)qq * 512 + hf * 256 + gl * 4) = v;
    }
}

// ---------------- launch ------------------------------------------------------
extern "C" void kernel_launch(void* const* d_in, const int* in_sizes, int n_in,
                              void* d_out, int out_size, void* d_ws, size_t ws_size,
                              hipStream_t stream) {
    const float* A    = (const float*)d_in[1];
    const int*   s1   = (const int*)  d_in[2];
    const int*   e1   = (const int*)  d_in[3];
    const int*   qb   = (const int*)  d_in[4];
    const int*   s2   = (const int*)  d_in[5];
    const int*   e2   = (const int*)  d_in[6];
    const float* W    = (const float*)d_in[7];
    const float* bias = (const float*)d_in[8];
    float*       out  = (float*)d_out;

    __bf16* WTf    = (__bf16*)d_ws;                                   // 512 KB
    int*    cnt    = (int*)((char*)d_ws + (1 << 20));                 // 64 KB
    int*    bucket = (int*)((char*)d_ws + (1 << 20) + (1 << 16));     // 2 MB

    wtf_kernel <<<dim3(32, 8), dim3(32, 32), 0, stream>>>(W, WTf, cnt);
    index_zero <<<dim3(NQ_ / 64), dim3(256), 0, stream>>>(s1, e1, s2, e2, qb, cnt, bucket, out);
    gemm_kernel<<<dim3(M_TOT / 64), dim3(512), 0, stream>>>(A, WTf, bias, cnt, bucket, out);
}

// Round 9
// 132.516 us; speedup vs baseline: 1.1675x; 1.0105x over previous
//
#include <hip/hip_runtime.h>
#include <hip/hip_bf16.h>
#include <stdint.h>

#define S_LEN 2048
#define D_DIM 1024
#define P_DIM 256
#define NQ_   8192
#define M_TOT 16384  // B*S
#define CAP 32       // max span-endpoints per H row
#define HS  260      // padded f32 row stride for H tile in LDS

typedef __attribute__((ext_vector_type(4))) float  f32x4;
typedef __attribute__((ext_vector_type(8))) __bf16 bf16x8;

// ============================================================================
// Fragment spec (harness-verified, lane l = q*16+lm):
//   A-frag(mi,kt,kh): lane l elem e = A[m0+mi*16+lm][kt*64+(kh*4+q)*8+e]
//     in LDS at (mi*32+kt*2+kh)*512 + qp*128 + (lm^(qp<<1))*8   (bank swizzle)
//   B-frag(c16,kt,kh) in WTf at (c16*32+kt*2+kh)*512 + l*8:
//     lane l elem e = W[kt*64+(kh*4+q)*8+e][c16*16+lm]
// ============================================================================

// ---------------- Kernel 0: W [1024][256] f32 -> WTf (fragment order) ---------
// Also zeroes the 16384-entry row-bucket counters.
__global__ __launch_bounds__(1024) void wtf_kernel(const float* __restrict__ W,
                                                   __bf16* __restrict__ WTf,
                                                   int* __restrict__ cnt) {
    __shared__ float tile[32][33];
    const int bx = blockIdx.x;            // k0 = bx*32 -> (kt = bx>>1, kh = bx&1)
    const int by = blockIdx.y;            // n0 = by*32 -> c16 in {2by, 2by+1}
    const int k0 = bx * 32, n0 = by * 32;
    const int tx = threadIdx.x, ty = threadIdx.y;
    const int g = (by * 32 + bx) * 1024 + ty * 32 + tx;
    if (g < M_TOT) cnt[g] = 0;
    tile[ty][tx] = W[(k0 + ty) * P_DIM + (n0 + tx)];   // coalesced
    __syncthreads();
    const int t = ty * 32 + tx;
    if (t < 128) {                        // 2 c16r * 4 q * 16 lm writers
        const int c16r = t >> 6, q = (t >> 4) & 3, lm = t & 15;
        bf16x8 v;
        #pragma unroll
        for (int e = 0; e < 8; ++e) v[e] = (__bf16)tile[q * 8 + e][c16r * 16 + lm];
        const int c16 = by * 2 + c16r;
        const int ts  = bx >> 1, kh = bx & 1;
        *(bf16x8*)(WTf + (size_t)((c16 * 32 + ts * 2 + kh) * 512 + (q * 16 + lm) * 8)) = v;
    }
}

// ---------------- Kernel 1: inverted span index + invalid-span zeroing --------
__global__ __launch_bounds__(256) void index_zero(const int* __restrict__ s1,
                                                  const int* __restrict__ e1,
                                                  const int* __restrict__ s2,
                                                  const int* __restrict__ e2,
                                                  const int* __restrict__ qb,
                                                  int* __restrict__ cnt,
                                                  int* __restrict__ bucket,
                                                  float* __restrict__ out) {
    const int lane = threadIdx.x & 63;
    const int q    = blockIdx.x * 64 + lane;
    const int set  = threadIdx.x >> 7;
    const int half = (threadIdx.x >> 6) & 1;
    const int b    = qb[q];
    const int s = set ? s2[q] : s1[q];
    const int e = set ? e2[q] : e1[q];
    if (!half && e >= s) {
        int r = b * S_LEN + s;
        int k = atomicAdd(&cnt[r], 1); if (k < CAP) bucket[r * CAP + k] = (q << 2) | (set << 1);
        r = b * S_LEN + e;
        k = atomicAdd(&cnt[r], 1);     if (k < CAP) bucket[r * CAP + k] = (q << 2) | (set << 1) | 1;
    }
    unsigned long long mask = __ballot(e < s);
    const int bqw = blockIdx.x * 64;
    const float4 z = make_float4(0.f, 0.f, 0.f, 0.f);
    while (mask) {
        const int j = __ffsll(mask) - 1;
        mask &= mask - 1;
        float* dst = out + (size_t)set * (NQ_ * 512) + (size_t)(bqw + j) * 512 + half * 256;
        ((float4*)dst)[lane] = z;
    }
}

// ---------------- Kernel 2: quarter-pipelined cvt+GEMM + span scatter ---------
// 256 blocks x 512 thr (1 block/CU). BM=64, wave w -> all 64 rows x cols
// [w*32,+32). A-panel split into 4 K-quarters (4 kt = 64 KB each), software
// pipelined (T14 issue-early/write-late): quarter q+1's global loads are in
// flight while quarter q computes, so the A HBM stream runs continuously
// under the L2-bound K-loop instead of serializing before it. Per-block
// quarter stagger ph4 de-convoys the shared WTf sweep. B in register triple
// buffer (literal indices), first two rounds issued before any A traffic.
__global__ __launch_bounds__(512, 1) void gemm_kernel(const float*  __restrict__ A,
                                                      const __bf16* __restrict__ WTf,
                                                      const float*  __restrict__ bias,
                                                      const int*    __restrict__ cnt,
                                                      const int*    __restrict__ bucket,
                                                      float*        __restrict__ out) {
    __shared__ __align__(16) __bf16 Afl[65536];   // 128 KB A-panel fragments
    __shared__ int s_cnt[64];
    __shared__ int s_off[65];
    __shared__ int elist[64 * CAP];

    const int tid = threadIdx.x;
    const int w   = tid >> 6;             // wave 0..7
    const int l   = tid & 63;
    const int lm  = l & 15;
    const int q   = l >> 4;

    const int m0  = blockIdx.x * 64;
    const int ph4 = blockIdx.x & 3;       // quarter stagger

    // ---- B fragment pointers + register triple-buffer (literal indices) -----
    const __bf16* bp[2][2];
    #pragma unroll
    for (int ni = 0; ni < 2; ++ni)
        #pragma unroll
        for (int kh = 0; kh < 2; ++kh)
            bp[ni][kh] = WTf + (size_t)(((w * 2 + ni) * 32 + kh) * 512 + l * 8);

    bf16x8 bre[3][2][2];
    // compute-step T (0..15) -> kt = ((ph4 + T/4)&3)*4 + (T&3)
#define KT_OF(T) ((((ph4 + ((T) >> 2)) & 3) << 2) + ((T) & 3))
#define LOADB(B, T) {                                                         \
    const int kt_ = KT_OF(T);                                                 \
    _Pragma("unroll") for (int ni = 0; ni < 2; ++ni)                          \
        _Pragma("unroll") for (int kh = 0; kh < 2; ++kh)                      \
            bre[B][ni][kh] = *(const bf16x8*)(bp[ni][kh] + kt_ * 1024); }

    LOADB(0, 0)
    LOADB(1, 1)

    // ---- A staging: thread t -> row tid>>3, chunk-lane la = tid&7.
    // Quarter qq covers chunks c = qq*32 + it*8 + la, it = 0..3.
    const int r    = tid >> 3;
    const int la   = tid & 7;
    const int mi_s = r >> 4, lmr = r & 15;
    const float* asrc = A + (size_t)(m0 + r) * D_DIM;

    float4 fA[8], fB[8];
#define LOADQ(QQ, FR) {                                                       \
    _Pragma("unroll") for (int it = 0; it < 4; ++it) {                        \
        const int c = (QQ) * 32 + it * 8 + la;                                \
        FR[it * 2]     = *(const float4*)(asrc + c * 8);                      \
        FR[it * 2 + 1] = *(const float4*)(asrc + c * 8 + 4); } }
#define WRITEQ(QQ, FR) {                                                      \
    _Pragma("unroll") for (int it = 0; it < 4; ++it) {                        \
        const int c = (QQ) * 32 + it * 8 + la;                                \
        bf16x8 v;                                                             \
        v[0] = (__bf16)FR[it*2].x;   v[1] = (__bf16)FR[it*2].y;               \
        v[2] = (__bf16)FR[it*2].z;   v[3] = (__bf16)FR[it*2].w;               \
        v[4] = (__bf16)FR[it*2+1].x; v[5] = (__bf16)FR[it*2+1].y;             \
        v[6] = (__bf16)FR[it*2+1].z; v[7] = (__bf16)FR[it*2+1].w;             \
        const int kt = c >> 3, kh = (c >> 2) & 1, qp = c & 3;                 \
        const int slot = lmr ^ (qp << 1);                                     \
        *(bf16x8*)(&Afl[(mi_s * 32 + kt * 2 + kh) * 512 + qp * 128 + slot * 8]) = v; } }

    const int slotr = lm ^ (q << 1);
    const __bf16* abase = Afl + q * 128 + slotr * 8;   // + (mi*32+kt*2+kh)*512
    f32x4 acc[4][2] = {};

#define CSTEP(T) {                                                            \
    const int kt_ = KT_OF(T);                                                 \
    bf16x8 af[4][2];                                                          \
    _Pragma("unroll") for (int mi = 0; mi < 4; ++mi)                          \
        _Pragma("unroll") for (int kh = 0; kh < 2; ++kh)                      \
            af[mi][kh] = *(const bf16x8*)(abase + (mi * 32 + kt_ * 2 + kh) * 512); \
    _Pragma("unroll") for (int kh = 0; kh < 2; ++kh)                          \
        _Pragma("unroll") for (int mi = 0; mi < 4; ++mi)                      \
            _Pragma("unroll") for (int ni = 0; ni < 2; ++ni)                  \
                acc[mi][ni] = __builtin_amdgcn_mfma_f32_16x16x32_bf16(        \
                    af[mi][kh], bre[(T) % 3][ni][kh], acc[mi][ni], 0, 0, 0); }

    const int q0 = ph4, q1 = (ph4 + 1) & 3, q2 = (ph4 + 2) & 3, q3 = (ph4 + 3) & 3;

    LOADQ(q0, fA)
    LOADQ(q1, fB)                // in flight under q0's write + compute
    WRITEQ(q0, fA)               // counted vmcnt: waits fA only
    __syncthreads();             // quarter q0 visible
    LOADB(2, 2) CSTEP(0) LOADB(0, 3) CSTEP(1) LOADB(1, 4) CSTEP(2) LOADB(2, 5) CSTEP(3)
    WRITEQ(q1, fB)               // fB landed during q0 compute
    LOADQ(q2, fA)
    __syncthreads();
    LOADB(0, 6) CSTEP(4) LOADB(1, 7) CSTEP(5) LOADB(2, 8) CSTEP(6) LOADB(0, 9) CSTEP(7)
    WRITEQ(q2, fA)
    LOADQ(q3, fB)
    __syncthreads();
    LOADB(1, 10) CSTEP(8) LOADB(2, 11) CSTEP(9) LOADB(0, 12) CSTEP(10) LOADB(1, 13) CSTEP(11)
    WRITEQ(q3, fB)
    __syncthreads();
    LOADB(2, 14) CSTEP(12) LOADB(0, 15) CSTEP(13) CSTEP(14) CSTEP(15)

#undef CSTEP
#undef LOADQ
#undef WRITEQ
#undef LOADB
#undef KT_OF

    // ---- fused epilogue (hs overlays Afl; barrier first) --------------------
    __syncthreads();                       // all waves done reading Afl
    float* hs = (float*)Afl;               // 64 x HS f32 = 66.6 KB < 128 KB

    if (tid < 64) { int c = cnt[m0 + tid]; s_cnt[tid] = c < CAP ? c : CAP; }

    // D layout: row = mi*16 + q*4 + r, col = w*32 + ni*16 + lm
    #pragma unroll
    for (int ni = 0; ni < 2; ++ni) {
        const int col = w * 32 + ni * 16 + lm;
        const float bv = bias[col];
        #pragma unroll
        for (int mi = 0; mi < 4; ++mi) {
            const int rbase = mi * 16 + q * 4;
            #pragma unroll
            for (int rr = 0; rr < 4; ++rr)
                hs[(rbase + rr) * HS + col] = acc[mi][ni][rr] + bv;
        }
    }
    __syncthreads();
    if (tid == 0) {
        int a = 0;
        #pragma unroll 1
        for (int i = 0; i < 64; ++i) { s_off[i] = a; a += s_cnt[i]; }
        s_off[64] = a;
    }
    __syncthreads();
    if (tid < 64) {
        const int o = s_off[tid], c = s_cnt[tid];
        const int* bk = bucket + (size_t)(m0 + tid) * CAP;
        for (int k = 0; k < c; ++k)
            elist[o + k] = (tid << 15) | (bk[k] & 0x7fff);
    }
    __syncthreads();

    const int E   = s_off[64];
    const int grp = tid >> 6;
    const int gl  = tid & 63;
    #pragma unroll 1
    for (int j = grp; j < E; j += 8) {
        const int ent  = elist[j];
        const int rl   = ent >> 15;
        const int code = ent & 0x7fff;
        const int qq   = code >> 2;
        const int st   = (code >> 1) & 1;
        const int hf   = code & 1;
        const float4 v = *(const float4*)&hs[rl * HS + gl * 4];
        *(float4*)(out + (size_t)st * (NQ_ * 512) + (size_t)qq * 512 + hf * 256 + gl * 4) = v;
    }
}

// ---------------- launch ------------------------------------------------------
extern "C" void kernel_launch(void* const* d_in, const int* in_sizes, int n_in,
                              void* d_out, int out_size, void* d_ws, size_t ws_size,
                              hipStream_t stream) {
    const float* A    = (const float*)d_in[1];
    const int*   s1   = (const int*)  d_in[2];
    const int*   e1   = (const int*)  d_in[3];
    const int*   qb   = (const int*)  d_in[4];
    const int*   s2   = (const int*)  d_in[5];
    const int*   e2   = (const int*)  d_in[6];
    const float* W    = (const float*)d_in[7];
    const float* bias = (const float*)d_in[8];
    float*       out  = (float*)d_out;

    __bf16* WTf    = (__bf16*)d_ws;                                   // 512 KB
    int*    cnt    = (int*)((char*)d_ws + (1 << 20));                 // 64 KB
    int*    bucket = (int*)((char*)d_ws + (1 << 20) + (1 << 16));     // 2 MB

    wtf_kernel <<<dim3(32, 8), dim3(32, 32), 0, stream>>>(W, WTf, cnt);
    index_zero <<<dim3(NQ_ / 64), dim3(256), 0, stream>>>(s1, e1, s2, e2, qb, cnt, bucket, out);
    gemm_kernel<<<dim3(M_TOT / 64), dim3(512), 0, stream>>>(A, WTf, bias, cnt, bucket, out);
}